// Round 11
// baseline (252.031 us; speedup 1.0000x reference)
//
#include <hip/hip_runtime.h>
#include <hip/hip_bf16.h>
#include <math.h>

#define N_NODES 4096
#define N_EDGES 131072
#define BCAP 80                        // bucket capacity per row (Poisson(32): P(>80)~1e-12)
#define DIN 148
#define DHID 128
#define DOUT 148
#define KP 160
#define NITER 8                        // must be even (fixed LDS double-buffer)

typedef __attribute__((ext_vector_type(8))) _Float16 half8;
typedef __attribute__((ext_vector_type(4))) float f32x4;

__device__ inline float h2f(unsigned e) {
    union { unsigned short u; _Float16 h; } cv;
    cv.u = (unsigned short)(e & 0xffffu);
    return (float)cv.h;
}

// ---------------- prep: weight transposes + dedup into fixed-stride buckets ----------------
__global__ __launch_bounds__(256) void prep_kernel(const int* __restrict__ ei,
                                                   const float* __restrict__ W1,
                                                   const float* __restrict__ Wd,
                                                   float* __restrict__ W1T,
                                                   float* __restrict__ WdT,
                                                   unsigned* __restrict__ bitmap,
                                                   unsigned* __restrict__ bucket,
                                                   int* __restrict__ rowdeg,
                                                   int* __restrict__ coldeg) {
    int gtid = blockIdx.x * 256 + threadIdx.x;          // 0..131071
    if (gtid < DIN * DHID) {                            // W1T[k*128+d] = W1[d*148+k]
        int kk = gtid >> 7, d = gtid & 127;
        W1T[gtid] = W1[d * DIN + kk];
    } else if (gtid < DIN * DHID + DHID * DOUT) {       // WdT[h*148+o] = Wd[o*128+h]
        int i2 = gtid - DIN * DHID;
        int h = i2 / DOUT, o = i2 - h * DOUT;
        WdT[i2] = Wd[o * DHID + h];
    }
    int i = ei[gtid] & (N_NODES - 1);
    int j = ei[gtid + N_EDGES] & (N_NODES - 1);
    unsigned pos = (unsigned)i * (unsigned)N_NODES + (unsigned)j;
    unsigned w = pos >> 5, m = 1u << (pos & 31u);
    unsigned old = atomicOr(&bitmap[w], m);
    if (!(old & m)) {
        int p = atomicAdd(&rowdeg[i], 1);
        if (p < BCAP) bucket[i * BCAP + p] = (unsigned)j;
        atomicAdd(&coldeg[j], 1);
    }
}

// ------ finalize: pack coefs + acoef + linear1 (output TRANSPOSED Bt[128][4096]) ------
__global__ __launch_bounds__(256) void finalize_kernel(unsigned* __restrict__ bucket,
                                                       const int* __restrict__ rowdeg,
                                                       const int* __restrict__ coldeg,
                                                       float* __restrict__ acoef,
                                                       const float* __restrict__ a_param,
                                                       const float* __restrict__ nf,
                                                       const float* __restrict__ W1T,
                                                       const float* __restrict__ b1,
                                                       float* __restrict__ Bt) {
    int tid = threadIdx.x, bid = blockIdx.x;            // 512 blocks, 8 nodes each
    int r0 = bid * 8;
    // pack: (col<<16) | f16(rsqrt(rowdeg[col])) ; zero-pad to multiple of 8
    for (int idx = tid; idx < 8 * BCAP; idx += 256) {
        int r = r0 + idx / BCAP, q = idx % BCAP;
        int dg = min(rowdeg[r], BCAP);
        int dg8 = (dg + 7) & ~7;
        if (q < dg) {
            unsigned col = bucket[r * BCAP + q];
            int rd = rowdeg[col];
            float rsj = (rd > 0) ? rsqrtf((float)rd) : 0.0f;
            union { _Float16 h; unsigned short u; } cv;
            cv.h = (_Float16)rsj;
            bucket[r * BCAP + q] = (col << 16) | (unsigned)cv.u;
        } else if (q < dg8) {
            bucket[r * BCAP + q] = 0u;                  // coef 0 -> contributes 0
        }
    }
    if (tid < 8) {
        int r = r0 + tid;
        float alpha = 0.5f + 0.5f * tanhf(2.0f * a_param[0]);
        int cd = coldeg[r];
        acoef[r] = (cd > 0) ? alpha * rsqrtf((float)cd) : 0.0f;
    }
    // linear1: 8 nodes, features staged in LDS, W1T coalesced; result staged + transposed
    __shared__ float sA[8 * 152];
    __shared__ float sOut[8][132];                      // pad 132: conflict-free transpose
    for (int idx = tid; idx < 8 * DIN; idx += 256) {
        int nd = idx / DIN, c = idx - nd * DIN;
        sA[nd * 152 + c] = nf[(r0 + nd) * DIN + c];
    }
    __syncthreads();
    {
        int half = tid >> 7, d = tid & 127;
        float a0 = 0.f, a1 = 0.f, a2 = 0.f, a3 = 0.f;
        const float* sb8 = sA + half * 4 * 152;
        for (int kk = 0; kk < DIN; ++kk) {
            float wv = W1T[kk * DHID + d];
            a0 += sb8[0 * 152 + kk] * wv;
            a1 += sb8[1 * 152 + kk] * wv;
            a2 += sb8[2 * 152 + kk] * wv;
            a3 += sb8[3 * 152 + kk] * wv;
        }
        float bb = b1[d];
        sOut[half * 4 + 0][d] = a0 + bb;
        sOut[half * 4 + 1][d] = a1 + bb;
        sOut[half * 4 + 2][d] = a2 + bb;
        sOut[half * 4 + 3][d] = a3 + bb;
    }
    __syncthreads();
    for (int idx = tid; idx < 8 * DHID; idx += 256) {
        int ff = idx >> 3, n = idx & 7;
        Bt[ff * 4096 + r0 + n] = sOut[n][ff];
    }
}

// ---- solve: one block per feature column; all NITER iterations in LDS; per-column extrapolation ----
__global__ __launch_bounds__(512) void solve_kernel(const float* __restrict__ Bt,
                                                    float* __restrict__ xT,
                                                    const unsigned* __restrict__ cc,
                                                    const int* __restrict__ rowdeg,
                                                    const float* __restrict__ acoef) {
    __shared__ float xa[N_NODES];                       // 16 KB
    __shared__ float xb[N_NODES];                       // 16 KB
    __shared__ double sred[1024];                       // 8 KB reduction scratch
    __shared__ float sbc;
    int f = blockIdx.x;                                 // feature 0..127
    int tid = threadIdx.x;
    int r0 = tid * 8;                                   // 8 rows per thread
    float Bv[8], ac[8], lastv[8], prevv[8], prev2v[8];
    int ne[8];
    const float* __restrict__ bp = Bt + f * N_NODES;
#pragma unroll
    for (int i = 0; i < 8; ++i) {
        Bv[i] = bp[r0 + i];
        ac[i] = acoef[r0 + i];
        ne[i] = (min(rowdeg[r0 + i], BCAP) + 7) & ~7;
        xa[r0 + i] = Bv[i];
        lastv[i] = Bv[i]; prevv[i] = Bv[i]; prev2v[i] = Bv[i];
    }
    __syncthreads();

    auto iter = [&](const float* __restrict__ src, float* __restrict__ dst) {
        float nv[8];
#pragma unroll
        for (int i = 0; i < 8; ++i) {
            const uint4* __restrict__ q = (const uint4*)(cc + (r0 + i) * BCAP);
            float a = 0.f;
            for (int t = 0; t < ne[i]; t += 8) {
                uint4 qa = q[t >> 2], qb = q[(t >> 2) + 1];
                a += h2f(qa.x) * src[qa.x >> 16] + h2f(qa.y) * src[qa.y >> 16]
                   + h2f(qa.z) * src[qa.z >> 16] + h2f(qa.w) * src[qa.w >> 16]
                   + h2f(qb.x) * src[qb.x >> 16] + h2f(qb.y) * src[qb.y >> 16]
                   + h2f(qb.z) * src[qb.z >> 16] + h2f(qb.w) * src[qb.w >> 16];
            }
            nv[i] = Bv[i] + ac[i] * a;
        }
#pragma unroll
        for (int i = 0; i < 8; ++i) {
            dst[r0 + i] = nv[i];
            prev2v[i] = prevv[i]; prevv[i] = lastv[i]; lastv[i] = nv[i];
        }
        __syncthreads();
    };
#pragma unroll
    for (int it = 0; it < NITER / 2; ++it) { iter(xa, xb); iter(xb, xa); }

    // per-column Perron extrapolation: lam = <dn,dp>/<dp,dp>, x* = last + s*(last-prev)
    double s0 = 0.0, s1 = 0.0;
#pragma unroll
    for (int i = 0; i < 8; ++i) {
        float dp = prevv[i] - prev2v[i];
        float dn = lastv[i] - prevv[i];
        s0 += (double)dp * (double)dp;
        s1 += (double)dn * (double)dp;
    }
    sred[tid] = s0; sred[512 + tid] = s1;
    __syncthreads();
    for (int off = 256; off > 0; off >>= 1) {
        if (tid < off) {
            sred[tid] += sred[tid + off];
            sred[512 + tid] += sred[512 + tid + off];
        }
        __syncthreads();
    }
    if (tid == 0) {
        double d0 = sred[0], d1 = sred[512];
        float lam = (d0 > 1e-30) ? (float)(d1 / d0) : 0.0f;
        lam = fminf(fmaxf(lam, -0.9f), 0.99f);          // s in [-0.474, 99]
        sbc = lam / (1.0f - lam);
    }
    __syncthreads();
    float s = sbc;
#pragma unroll
    for (int i = 0; i < 8; ++i)
        xT[f * N_NODES + r0 + i] = lastv[i] + s * (lastv[i] - prevv[i]);
}

// ---------------- post: linear_d (from transposed xT) + f16 convert + pool ----------------
__global__ __launch_bounds__(256) void post_kernel(const float* __restrict__ xT,
                                                   const float* __restrict__ WdT,
                                                   const float* __restrict__ bd,
                                                   _Float16* __restrict__ yH,
                                                   unsigned* __restrict__ mcolu) {
    int tid = threadIdx.x, bid = blockIdx.x;            // 512 blocks, 8 nodes each
    int r0 = bid * 8;
    __shared__ float sx[8 * DHID];                      // [node][feature]
    for (int idx = tid; idx < 8 * DHID; idx += 256) {
        int ff = idx >> 3, n = idx & 7;
        sx[n * DHID + ff] = xT[ff * N_NODES + r0 + n];
    }
    __syncthreads();
    if (tid < DOUT) {
        float acc[8];
#pragma unroll
        for (int nd = 0; nd < 8; ++nd) acc[nd] = 0.f;
        for (int h = 0; h < DHID; ++h) {
            float wv = WdT[h * DOUT + tid];
#pragma unroll
            for (int nd = 0; nd < 8; ++nd) acc[nd] += sx[nd * DHID + h] * wv;
        }
        float bb = bd[tid];
        float lm = 0.0f;                                // relu floor
#pragma unroll
        for (int nd = 0; nd < 8; ++nd) {
            float v = acc[nd] + bb;
            yH[(r0 + nd) * KP + tid] = (_Float16)v;
            lm = fmaxf(lm, v);
        }
        atomicMax(&mcolu[tid], __float_as_uint(lm));    // nonneg float == uint order
    } else {
        int i2 = tid - DOUT;                            // zero pad cols 148..159
        if (i2 < 8 * (KP - DOUT)) {
            int node = r0 + i2 / (KP - DOUT);
            int ccol = DOUT + i2 % (KP - DOUT);
            yH[node * KP + ccol] = (_Float16)0.0f;
        }
    }
}

// ---------------- simloss MFMA (528 tiles) + final outputs via last block ----------------
__global__ __launch_bounds__(256) void simloss_kernel(const _Float16* __restrict__ yH,
                                                      double* __restrict__ accd,
                                                      unsigned* __restrict__ cnt,
                                                      const unsigned* __restrict__ mcolu,
                                                      const float* __restrict__ W2,
                                                      const float* __restrict__ b2,
                                                      const float* __restrict__ a_param,
                                                      float* __restrict__ out) {
    int tid = threadIdx.x;
    int tb = blockIdx.x;
    int ti = 0, rem = tb;
    while (rem >= 32 - ti) { rem -= 32 - ti; ++ti; }
    int tj = ti + rem;
    int wid = tid >> 6, lane = tid & 63;
    int wr = wid >> 1, wc = wid & 1;
    int fr = lane & 15, kq = lane >> 4;
    const half8* __restrict__ ap =
        (const half8*)(yH + (size_t)(ti * 128 + wr * 64 + fr) * KP);
    const half8* __restrict__ bp =
        (const half8*)(yH + (size_t)(tj * 128 + wc * 64 + fr) * KP);
    f32x4 C[4][4];
#pragma unroll
    for (int m = 0; m < 4; ++m)
#pragma unroll
        for (int n = 0; n < 4; ++n) C[m][n] = (f32x4)0.0f;
#pragma unroll
    for (int kk = 0; kk < KP / 32; ++kk) {
        half8 a[4], bf[4];
#pragma unroll
        for (int m = 0; m < 4; ++m) a[m] = ap[m * 320 + kk * 4 + kq];
#pragma unroll
        for (int n = 0; n < 4; ++n) bf[n] = bp[n * 320 + kk * 4 + kq];
#pragma unroll
        for (int m = 0; m < 4; ++m)
#pragma unroll
            for (int n = 0; n < 4; ++n)
                C[m][n] = __builtin_amdgcn_mfma_f32_16x16x32_f16(a[m], bf[n], C[m][n], 0, 0, 0);
    }
    const float inv = 0.0883883476483184405f;           // 1/sqrt(128)
    float wgt = (ti == tj) ? 1.0f : 2.0f;
    float lsum = 0.0f;
    int rq = kq * 4;
#pragma unroll
    for (int m = 0; m < 4; ++m)
#pragma unroll
        for (int n = 0; n < 4; ++n)
#pragma unroll
            for (int reg = 0; reg < 4; ++reg) {
                int gi = ti * 128 + wr * 64 + m * 16 + rq + reg;
                int gj = tj * 128 + wc * 64 + n * 16 + fr;
                float v = C[m][n][reg] * inv;
                if (gi != gj && v > 0.0f) lsum += wgt * v;
            }
    for (int o2 = 32; o2 > 0; o2 >>= 1) lsum += __shfl_down(lsum, o2);
    __shared__ float ws[4];
    __shared__ bool lastblk;
    if ((tid & 63) == 0) ws[tid >> 6] = lsum;
    __syncthreads();
    if (tid == 0) {
        atomicAdd(&accd[0], (double)(ws[0] + ws[1] + ws[2] + ws[3]));
        __threadfence();
        unsigned r = __hip_atomic_fetch_add(&cnt[1], 1u, __ATOMIC_ACQ_REL,
                                            __HIP_MEMORY_SCOPE_AGENT);
        lastblk = (r == 527u);
    }
    __syncthreads();
    if (lastblk && tid < 64) {
        float alpha = 0.5f + 0.5f * tanhf(2.0f * a_param[0]);
        float oma = 1.0f - alpha;
        float s0 = 0.0f, s1 = 0.0f;
        for (int o = tid; o < DOUT; o += 64) {
            float p = __uint_as_float(mcolu[o]);        // already relu'd
            s0 += p * W2[o];
            s1 += p * W2[DOUT + o];
        }
        for (int off = 32; off > 0; off >>= 1) {
            s0 += __shfl_down(s0, off);
            s1 += __shfl_down(s1, off);
        }
        if (tid == 0) {
            double loss = __hip_atomic_load(&accd[0], __ATOMIC_RELAXED,
                                            __HIP_MEMORY_SCOPE_AGENT);
            out[0] = b2[0] + oma * s0;
            out[1] = b2[1] + oma * s1;
            out[2] = (float)(loss / (4096.0 * 4095.0));
        }
    }
}

extern "C" void kernel_launch(void* const* d_in, const int* in_sizes, int n_in,
                              void* d_out, int out_size, void* d_ws, size_t ws_size,
                              hipStream_t stream) {
    (void)in_sizes; (void)n_in; (void)out_size; (void)ws_size;
    const float* node_feat  = (const float*)d_in[0];
    const int*   edge_index = (const int*)d_in[1];   // harness converts int64 -> int32
    const float* W1         = (const float*)d_in[3];
    const float* b1         = (const float*)d_in[4];
    const float* a_param    = (const float*)d_in[5];
    const float* Wd         = (const float*)d_in[6];
    const float* bd         = (const float*)d_in[7];
    const float* W2         = (const float*)d_in[8];
    const float* b2         = (const float*)d_in[9];
    float*       out        = (float*)d_out;

    char* w = (char*)d_ws;
    size_t off = 0;
    auto alloc = [&](size_t bytes) -> char* {
        char* p = w + off;
        off = (off + bytes + 255) & ~(size_t)255;
        return p;
    };
    // zeroed region: accd, cnt, rowdeg, coldeg, mcolu, bitmap (single memset)
    double*   accd    = (double*)   alloc(8 * sizeof(double));   // [0]=loss
    unsigned* cnt     = (unsigned*) alloc(16 * sizeof(unsigned));// [1]=simloss done ctr
    int*      rowdeg  = (int*)      alloc(N_NODES * 4);
    int*      coldeg  = (int*)      alloc(N_NODES * 4);
    unsigned* mcolu   = (unsigned*) alloc(256 * 4);
    unsigned* bitmap  = (unsigned*) alloc((size_t)N_NODES * N_NODES / 8);  // 2 MB
    size_t zero_end = off;
    float*    acoef   = (float*)    alloc(N_NODES * 4);
    unsigned* bucket  = (unsigned*) alloc((size_t)N_NODES * BCAP * 4 + 512);
    float*    W1T     = (float*)    alloc(DIN * DHID * 4);
    float*    WdT     = (float*)    alloc(DHID * DOUT * 4);
    float*    Bt      = (float*)    alloc((size_t)DHID * N_NODES * 4);     // transposed
    float*    xT      = (float*)    alloc((size_t)DHID * N_NODES * 4);     // transposed
    _Float16* yH      = (_Float16*) alloc((size_t)N_NODES * KP * 2);

    hipMemsetAsync(w, 0, zero_end, stream);

    prep_kernel<<<N_EDGES / 256, 256, 0, stream>>>(edge_index, W1, Wd, W1T, WdT,
                                                   bitmap, bucket, rowdeg, coldeg);
    finalize_kernel<<<N_NODES / 8, 256, 0, stream>>>(bucket, rowdeg, coldeg, acoef,
                                                     a_param, node_feat, W1T, b1, Bt);
    solve_kernel<<<DHID, 512, 0, stream>>>(Bt, xT, bucket, rowdeg, acoef);
    post_kernel<<<N_NODES / 8, 256, 0, stream>>>(xT, WdT, bd, yH, mcolu);
    simloss_kernel<<<528, 256, 0, stream>>>(yH, accd, cnt, mcolu, W2, b2, a_param, out);
}

// Round 12
// 167.551 us; speedup vs baseline: 1.5042x; 1.5042x over previous
//
#include <hip/hip_runtime.h>
#include <hip/hip_bf16.h>
#include <math.h>

#define N_NODES 4096
#define N_EDGES 131072
#define BCAP 80                        // bucket capacity per row (Poisson(32): P(>80)~1e-12)
#define DIN 148
#define DHID 128
#define DOUT 148
#define KP 160
#define NITER 6

typedef __attribute__((ext_vector_type(8))) _Float16 half8;
typedef __attribute__((ext_vector_type(4))) float f32x4;

__device__ inline float h2f(unsigned e) {
    union { unsigned short u; _Float16 h; } cv;
    cv.u = (unsigned short)(e & 0xffffu);
    return (float)cv.h;
}

// ---------------- prep: weight transposes + dedup into fixed-stride buckets ----------------
__global__ __launch_bounds__(256) void prep_kernel(const int* __restrict__ ei,
                                                   const float* __restrict__ W1,
                                                   const float* __restrict__ Wd,
                                                   float* __restrict__ W1T,
                                                   float* __restrict__ WdT,
                                                   unsigned* __restrict__ bitmap,
                                                   unsigned* __restrict__ bucket,
                                                   int* __restrict__ rowdeg,
                                                   int* __restrict__ coldeg) {
    int gtid = blockIdx.x * 256 + threadIdx.x;          // 0..131071
    if (gtid < DIN * DHID) {                            // W1T[k*128+d] = W1[d*148+k]
        int kk = gtid >> 7, d = gtid & 127;
        W1T[gtid] = W1[d * DIN + kk];
    } else if (gtid < DIN * DHID + DHID * DOUT) {       // WdT[h*148+o] = Wd[o*128+h]
        int i2 = gtid - DIN * DHID;
        int h = i2 / DOUT, o = i2 - h * DOUT;
        WdT[i2] = Wd[o * DHID + h];
    }
    int i = ei[gtid] & (N_NODES - 1);
    int j = ei[gtid + N_EDGES] & (N_NODES - 1);
    unsigned pos = (unsigned)i * (unsigned)N_NODES + (unsigned)j;
    unsigned w = pos >> 5, m = 1u << (pos & 31u);
    unsigned old = atomicOr(&bitmap[w], m);
    if (!(old & m)) {
        int p = atomicAdd(&rowdeg[i], 1);
        if (p < BCAP) bucket[i * BCAP + p] = (unsigned)j;
        atomicAdd(&coldeg[j], 1);
    }
}

// ---------------- finalize: pack coefs in place (pad slots already zero) + acoef + linear1 ----------------
__global__ __launch_bounds__(256) void finalize_kernel(unsigned* __restrict__ bucket,
                                                       const int* __restrict__ rowdeg,
                                                       const int* __restrict__ coldeg,
                                                       float* __restrict__ acoef,
                                                       const float* __restrict__ a_param,
                                                       const float* __restrict__ nf,
                                                       const float* __restrict__ W1T,
                                                       const float* __restrict__ b1,
                                                       float* __restrict__ Bm) {
    int tid = threadIdx.x, bid = blockIdx.x;            // 512 blocks, 8 rows each
    int r0 = bid * 8;
    // pack: (col<<16) | f16(rsqrt(rowdeg[col])) ; slots >= dg stay zero (memset)
    for (int idx = tid; idx < 8 * BCAP; idx += 256) {
        int r = r0 + idx / BCAP, q = idx % BCAP;
        int dg = min(rowdeg[r], BCAP);
        if (q < dg) {
            unsigned col = bucket[r * BCAP + q];
            int rd = rowdeg[col];
            float rsj = (rd > 0) ? rsqrtf((float)rd) : 0.0f;
            union { _Float16 h; unsigned short u; } cv;
            cv.h = (_Float16)rsj;
            bucket[r * BCAP + q] = (col << 16) | (unsigned)cv.u;
        }
    }
    if (tid < 8) {
        int r = r0 + tid;
        float alpha = 0.5f + 0.5f * tanhf(2.0f * a_param[0]);
        int cd = coldeg[r];
        acoef[r] = (cd > 0) ? alpha * rsqrtf((float)cd) : 0.0f;
    }
    // linear1: 8 nodes, features staged in LDS, W1T coalesced
    __shared__ float sA[8 * 152];
    for (int idx = tid; idx < 8 * DIN; idx += 256) {
        int nd = idx / DIN, c = idx - nd * DIN;
        sA[nd * 152 + c] = nf[(r0 + nd) * DIN + c];
    }
    __syncthreads();
    int half = tid >> 7, d = tid & 127;
    float a0 = 0.f, a1 = 0.f, a2 = 0.f, a3 = 0.f;
    const float* sb8 = sA + half * 4 * 152;
    for (int kk = 0; kk < DIN; ++kk) {
        float wv = W1T[kk * DHID + d];
        a0 += sb8[0 * 152 + kk] * wv;
        a1 += sb8[1 * 152 + kk] * wv;
        a2 += sb8[2 * 152 + kk] * wv;
        a3 += sb8[3 * 152 + kk] * wv;
    }
    float bb = b1[d];
    int node0 = r0 + half * 4;
    Bm[(node0 + 0) * DHID + d] = a0 + bb;
    Bm[(node0 + 1) * DHID + d] = a1 + bb;
    Bm[(node0 + 2) * DHID + d] = a2 + bb;
    Bm[(node0 + 3) * DHID + d] = a3 + bb;
}

// ---- Richardson iteration: 1 row/wave, float2 lanes, 2-deep edge / 1-deep gather pipeline ----
template<bool LAST>
__global__ __launch_bounds__(256) void spmv_kernel(const float* __restrict__ xin,
                                                   float* __restrict__ xout,
                                                   const float* __restrict__ Bm,
                                                   const float* __restrict__ prev2,
                                                   const unsigned* __restrict__ cc,
                                                   const int* __restrict__ rowdeg,
                                                   const float* __restrict__ acoef,
                                                   double* __restrict__ accd) {
    int tid = threadIdx.x;
    int wid = __builtin_amdgcn_readfirstlane(tid >> 6); // wave id 0..3 (SGPR)
    int lane = tid & 63;
    int r = blockIdx.x * 4 + wid;                       // one row per wave
    int dg8 = (min(rowdeg[r], BCAP) + 7) & ~7;          // wave-uniform
    int nch = dg8 >> 3;                                 // 8-edge chunks (>=0)
    const uint4* __restrict__ q = (const uint4*)(cc + r * BCAP);
    const float2* __restrict__ x2 = (const float2*)xin;
    float ax = 0.f, ay = 0.f;
    // pipeline: edges 2 ahead, gathers 1 ahead (over-reads land in zeroed slack / next rows)
    uint4 qa0 = q[0], qb0 = q[1];
    float2 v0 = x2[(qa0.x >> 16) * 64 + lane];
    float2 v1 = x2[(qa0.y >> 16) * 64 + lane];
    float2 v2 = x2[(qa0.z >> 16) * 64 + lane];
    float2 v3 = x2[(qa0.w >> 16) * 64 + lane];
    float2 v4 = x2[(qb0.x >> 16) * 64 + lane];
    float2 v5 = x2[(qb0.y >> 16) * 64 + lane];
    float2 v6 = x2[(qb0.z >> 16) * 64 + lane];
    float2 v7 = x2[(qb0.w >> 16) * 64 + lane];
    uint4 qa1 = q[2], qb1 = q[3];
    for (int c = 0; c < nch; ++c) {
        float2 w0 = x2[(qa1.x >> 16) * 64 + lane];      // gathers for chunk c+1
        float2 w1 = x2[(qa1.y >> 16) * 64 + lane];
        float2 w2 = x2[(qa1.z >> 16) * 64 + lane];
        float2 w3 = x2[(qa1.w >> 16) * 64 + lane];
        float2 w4 = x2[(qb1.x >> 16) * 64 + lane];
        float2 w5 = x2[(qb1.y >> 16) * 64 + lane];
        float2 w6 = x2[(qb1.z >> 16) * 64 + lane];
        float2 w7 = x2[(qb1.w >> 16) * 64 + lane];
        uint4 na = q[2 * c + 4], nb = q[2 * c + 5];     // edges for chunk c+2
        float c0 = h2f(qa0.x), c1 = h2f(qa0.y), c2f = h2f(qa0.z), c3 = h2f(qa0.w);
        float c4 = h2f(qb0.x), c5 = h2f(qb0.y), c6 = h2f(qb0.z), c7 = h2f(qb0.w);
        ax += c0 * v0.x + c1 * v1.x + c2f * v2.x + c3 * v3.x
            + c4 * v4.x + c5 * v5.x + c6 * v6.x + c7 * v7.x;
        ay += c0 * v0.y + c1 * v1.y + c2f * v2.y + c3 * v3.y
            + c4 * v4.y + c5 * v5.y + c6 * v6.y + c7 * v7.y;
        qa0 = qa1; qb0 = qb1; qa1 = na; qb1 = nb;
        v0 = w0; v1 = w1; v2 = w2; v3 = w3;
        v4 = w4; v5 = w5; v6 = w6; v7 = w7;
    }
    float ac = acoef[r];
    int idx = r * 64 + lane;
    float2 b = ((const float2*)Bm)[idx];
    float vx = b.x + ac * ax, vy = b.y + ac * ay;
    ((float2*)xout)[idx] = make_float2(vx, vy);
    if (LAST) {
        float2 xp = ((const float2*)xin)[idx];
        float2 p2 = ((const float2*)prev2)[idx];
        float dpx = xp.x - p2.x, dpy = xp.y - p2.y;
        float dnx = vx - xp.x, dny = vy - xp.y;
        double s0 = (double)dpx * dpx + (double)dpy * dpy;
        double s1 = (double)dnx * dpx + (double)dny * dpy;
        __shared__ double sh0[256], sh1[256];
        sh0[tid] = s0; sh1[tid] = s1;
        __syncthreads();
        for (int off = 128; off > 0; off >>= 1) {
            if (tid < off) { sh0[tid] += sh0[tid + off]; sh1[tid] += sh1[tid + off]; }
            __syncthreads();
        }
        if (tid == 0) { atomicAdd(&accd[1], sh0[0]); atomicAdd(&accd[2], sh1[0]); }
    }
}

// ---------------- extrap + linear_d + f16 convert + pool (atomicMax) ----------------
__global__ __launch_bounds__(256) void post_kernel(const float* __restrict__ last,
                                                   const float* __restrict__ prev,
                                                   const double* __restrict__ accd,
                                                   const float* __restrict__ WdT,
                                                   const float* __restrict__ bd,
                                                   _Float16* __restrict__ yH,
                                                   unsigned* __restrict__ mcolu) {
    int tid = threadIdx.x, bid = blockIdx.x;
    double d0 = accd[1], d1 = accd[2];
    float lam = (d0 > 0.0) ? (float)(d1 / d0) : 0.0f;
    float den = 1.0f - lam;
    if (fabsf(den) < 1e-4f) den = (den < 0.0f) ? -1e-4f : 1e-4f;
    float sf = fminf(fmaxf(lam / den, -1e4f), 1e4f);
    __shared__ float sx[8 * DHID];
    for (int idx = tid; idx < 8 * DHID; idx += 256) {
        int node = bid * 8 + (idx >> 7), ccol = idx & 127;
        float l = last[node * DHID + ccol];
        sx[idx] = l + sf * (l - prev[node * DHID + ccol]);
    }
    __syncthreads();
    if (tid < DOUT) {
        float acc[8];
#pragma unroll
        for (int nd = 0; nd < 8; ++nd) acc[nd] = 0.f;
        for (int h = 0; h < DHID; ++h) {
            float wv = WdT[h * DOUT + tid];
#pragma unroll
            for (int nd = 0; nd < 8; ++nd) acc[nd] += sx[nd * DHID + h] * wv;
        }
        float bb = bd[tid];
        float lm = 0.0f;                                // relu floor
#pragma unroll
        for (int nd = 0; nd < 8; ++nd) {
            int node = bid * 8 + nd;
            float v = acc[nd] + bb;
            yH[node * KP + tid] = (_Float16)v;
            lm = fmaxf(lm, v);
        }
        atomicMax(&mcolu[tid], __float_as_uint(lm));    // nonneg float == uint order
    } else {
        int i2 = tid - DOUT;                            // zero pad cols 148..159
        if (i2 < 8 * (KP - DOUT)) {
            int node = bid * 8 + i2 / (KP - DOUT);
            int ccol = DOUT + i2 % (KP - DOUT);
            yH[node * KP + ccol] = (_Float16)0.0f;
        }
    }
}

// ---------------- simloss MFMA (528 tiles) + final outputs via last block ----------------
__global__ __launch_bounds__(256) void simloss_kernel(const _Float16* __restrict__ yH,
                                                      double* __restrict__ accd,
                                                      unsigned* __restrict__ cnt,
                                                      const unsigned* __restrict__ mcolu,
                                                      const float* __restrict__ W2,
                                                      const float* __restrict__ b2,
                                                      const float* __restrict__ a_param,
                                                      float* __restrict__ out) {
    int tid = threadIdx.x;
    int tb = blockIdx.x;
    int ti = 0, rem = tb;
    while (rem >= 32 - ti) { rem -= 32 - ti; ++ti; }
    int tj = ti + rem;
    int wid = tid >> 6, lane = tid & 63;
    int wr = wid >> 1, wc = wid & 1;
    int fr = lane & 15, kq = lane >> 4;
    const half8* __restrict__ ap =
        (const half8*)(yH + (size_t)(ti * 128 + wr * 64 + fr) * KP);
    const half8* __restrict__ bp =
        (const half8*)(yH + (size_t)(tj * 128 + wc * 64 + fr) * KP);
    f32x4 C[4][4];
#pragma unroll
    for (int m = 0; m < 4; ++m)
#pragma unroll
        for (int n = 0; n < 4; ++n) C[m][n] = (f32x4)0.0f;
#pragma unroll
    for (int kk = 0; kk < KP / 32; ++kk) {
        half8 a[4], bf[4];
#pragma unroll
        for (int m = 0; m < 4; ++m) a[m] = ap[m * 320 + kk * 4 + kq];
#pragma unroll
        for (int n = 0; n < 4; ++n) bf[n] = bp[n * 320 + kk * 4 + kq];
#pragma unroll
        for (int m = 0; m < 4; ++m)
#pragma unroll
            for (int n = 0; n < 4; ++n)
                C[m][n] = __builtin_amdgcn_mfma_f32_16x16x32_f16(a[m], bf[n], C[m][n], 0, 0, 0);
    }
    const float inv = 0.0883883476483184405f;           // 1/sqrt(128)
    float wgt = (ti == tj) ? 1.0f : 2.0f;
    float lsum = 0.0f;
    int rq = kq * 4;
#pragma unroll
    for (int m = 0; m < 4; ++m)
#pragma unroll
        for (int n = 0; n < 4; ++n)
#pragma unroll
            for (int reg = 0; reg < 4; ++reg) {
                int gi = ti * 128 + wr * 64 + m * 16 + rq + reg;
                int gj = tj * 128 + wc * 64 + n * 16 + fr;
                float v = C[m][n][reg] * inv;
                if (gi != gj && v > 0.0f) lsum += wgt * v;
            }
    for (int o2 = 32; o2 > 0; o2 >>= 1) lsum += __shfl_down(lsum, o2);
    __shared__ float ws[4];
    __shared__ bool lastblk;
    if ((tid & 63) == 0) ws[tid >> 6] = lsum;
    __syncthreads();
    if (tid == 0) {
        atomicAdd(&accd[0], (double)(ws[0] + ws[1] + ws[2] + ws[3]));
        __threadfence();
        unsigned r = __hip_atomic_fetch_add(&cnt[1], 1u, __ATOMIC_ACQ_REL,
                                            __HIP_MEMORY_SCOPE_AGENT);
        lastblk = (r == 527u);
    }
    __syncthreads();
    if (lastblk && tid < 64) {
        float alpha = 0.5f + 0.5f * tanhf(2.0f * a_param[0]);
        float oma = 1.0f - alpha;
        float s0 = 0.0f, s1 = 0.0f;
        for (int o = tid; o < DOUT; o += 64) {
            float p = __uint_as_float(mcolu[o]);        // already relu'd
            s0 += p * W2[o];
            s1 += p * W2[DOUT + o];
        }
        for (int off = 32; off > 0; off >>= 1) {
            s0 += __shfl_down(s0, off);
            s1 += __shfl_down(s1, off);
        }
        if (tid == 0) {
            double loss = __hip_atomic_load(&accd[0], __ATOMIC_RELAXED,
                                            __HIP_MEMORY_SCOPE_AGENT);
            out[0] = b2[0] + oma * s0;
            out[1] = b2[1] + oma * s1;
            out[2] = (float)(loss / (4096.0 * 4095.0));
        }
    }
}

extern "C" void kernel_launch(void* const* d_in, const int* in_sizes, int n_in,
                              void* d_out, int out_size, void* d_ws, size_t ws_size,
                              hipStream_t stream) {
    (void)in_sizes; (void)n_in; (void)out_size; (void)ws_size;
    const float* node_feat  = (const float*)d_in[0];
    const int*   edge_index = (const int*)d_in[1];   // harness converts int64 -> int32
    const float* W1         = (const float*)d_in[3];
    const float* b1         = (const float*)d_in[4];
    const float* a_param    = (const float*)d_in[5];
    const float* Wd         = (const float*)d_in[6];
    const float* bd         = (const float*)d_in[7];
    const float* W2         = (const float*)d_in[8];
    const float* b2         = (const float*)d_in[9];
    float*       out        = (float*)d_out;

    char* w = (char*)d_ws;
    size_t off = 0;
    auto alloc = [&](size_t bytes) -> char* {
        char* p = w + off;
        off = (off + bytes + 255) & ~(size_t)255;
        return p;
    };
    // zeroed region: accd, cnt, rowdeg, coldeg, mcolu, bitmap, bucket(+slack)
    double*   accd    = (double*)   alloc(8 * sizeof(double));   // [0]=loss,[1,2]=dots
    unsigned* cnt     = (unsigned*) alloc(16 * sizeof(unsigned));// [1]=simloss done ctr
    int*      rowdeg  = (int*)      alloc(N_NODES * 4);
    int*      coldeg  = (int*)      alloc(N_NODES * 4);
    unsigned* mcolu   = (unsigned*) alloc(256 * 4);
    unsigned* bitmap  = (unsigned*) alloc((size_t)N_NODES * N_NODES / 8);    // 2 MB
    unsigned* bucket  = (unsigned*) alloc((size_t)N_NODES * BCAP * 4 + 1024); // 1.25 MB + slack
    size_t zero_end = off;
    float*    acoef   = (float*)    alloc(N_NODES * 4);
    float*    W1T     = (float*)    alloc(DIN * DHID * 4);
    float*    WdT     = (float*)    alloc(DHID * DOUT * 4);
    float*    Bm      = (float*)    alloc(N_NODES * DHID * 4);
    float*    Y0      = (float*)    alloc(N_NODES * DHID * 4);
    float*    Y1      = (float*)    alloc(N_NODES * DHID * 4);
    float*    Y2      = (float*)    alloc(N_NODES * DHID * 4);
    _Float16* yH      = (_Float16*) alloc((size_t)N_NODES * KP * 2);

    hipMemsetAsync(w, 0, zero_end, stream);

    prep_kernel<<<N_EDGES / 256, 256, 0, stream>>>(edge_index, W1, Wd, W1T, WdT,
                                                   bitmap, bucket, rowdeg, coldeg);
    finalize_kernel<<<N_NODES / 8, 256, 0, stream>>>(bucket, rowdeg, coldeg, acoef,
                                                     a_param, node_feat, W1T, b1, Bm);

    float* rot[3] = {Y0, Y1, Y2};
    const float* cur = Bm;
    for (int it = 0; it < NITER - 1; ++it) {
        float* dst = rot[it % 3];
        spmv_kernel<false><<<N_NODES / 4, 256, 0, stream>>>(cur, dst, Bm, nullptr, bucket,
                                                            rowdeg, acoef, accd);
        cur = dst;
    }
    float* lastb = rot[(NITER - 1) % 3];
    float* prevb = rot[(NITER - 2) % 3];
    float* prev2 = rot[(NITER - 3) % 3];
    spmv_kernel<true><<<N_NODES / 4, 256, 0, stream>>>(cur, lastb, Bm, prev2, bucket,
                                                       rowdeg, acoef, accd);

    post_kernel<<<N_NODES / 8, 256, 0, stream>>>(lastb, prevb, accd, WdT, bd, yH, mcolu);
    simloss_kernel<<<528, 256, 0, stream>>>(yH, accd, cnt, mcolu, W2, b2, a_param, out);
}